// Round 20
// baseline (73.946 us; speedup 1.0000x reference)
//
#include <hip/hip_runtime.h>
#include <hip/hip_bf16.h>

#define NROWS 8192
#define NDIM  256
#define KNN   8
#define TCOL  32                          // j-cols per LDS tile (16 KiB)
#define BLK_ROWS 128                      // 4 waves x 32 rows (R=1)
#define JSPLIT 16
#define JRANGE (NROWS / JSPLIT)           // 512
#define NBX    (NROWS / BLK_ROWS)         // 64 row-blocks

typedef __attribute__((ext_vector_type(8)))  short bf16x8;
typedef __attribute__((ext_vector_type(16))) float f32x16;

// ---- workspace layout (bytes) ----
// ebT chunk-major: ushort ebT[32][NROWS][8] — chunk c holds dims 8c..8c+7.
#define WS_EBT 0                          // 4 MiB
#define WS_SQN (4*1024*1024)              // 32 KiB
#define WS_PCS (WS_SQN + 32*1024)         // 256 x 256 f32 = 256 KiB
#define WS_S2P (WS_PCS + 256*1024)        // 256 f32 = 1 KiB
#define WS_ACC (WS_S2P + 1024)            // gacc[0]=sum8 [1]=S2 [2]=Q [3]=cnt
#define WS_KNN (WS_ACC + 1024)            // [16][NROWS][KNN] f32 = 4 MiB

// e -> bf16 chunk-major (LDS-staged transpose -> coalesced 512B writes),
// per-row norms, per-block colsum/S2 partials. Block 0 zeroes gacc.
__global__ void k_prep(const float* __restrict__ e,
                       ushort* __restrict__ ebt,
                       float* __restrict__ sqn,
                       float* __restrict__ pcs,
                       float* __restrict__ s2p,
                       float* __restrict__ gacc) {
  __shared__ ushort tbuf[32 * 256];       // 16 KiB transpose tile
  __shared__ float  lcs[NDIM];
  __shared__ float  s2red[4];
  char* const traw = reinterpret_cast<char*>(&tbuf[0]);

  const int tid  = threadIdx.x;
  const int lane = tid & 63;
  const int wv   = tid >> 6;
  const int rb   = blockIdx.x * 32;
  if (blockIdx.x == 0 && tid < 4) ((int*)gacc)[tid] = 0;
  lcs[tid] = 0.f;
  __syncthreads();

  const int g    = lane >> 1;             // 16B granule 0..31
  const int half = lane & 1;
  float4 cs = {0.f, 0.f, 0.f, 0.f};
  float s2loc = 0.f;
  #pragma unroll
  for (int r = 0; r < 8; ++r) {
    const int rl  = wv * 8 + r;
    const int row = rb + rl;
    const float4 v = *reinterpret_cast<const float4*>(e + (size_t)row * NDIM + lane * 4);
    ushort4 o;
    __hip_bfloat16 b0 = __float2bfloat16(v.x), b1 = __float2bfloat16(v.y);
    __hip_bfloat16 b2 = __float2bfloat16(v.z), b3 = __float2bfloat16(v.w);
    o.x = *reinterpret_cast<ushort*>(&b0); o.y = *reinterpret_cast<ushort*>(&b1);
    o.z = *reinterpret_cast<ushort*>(&b2); o.w = *reinterpret_cast<ushort*>(&b3);
    *reinterpret_cast<ushort4*>(
        traw + rl * 512 + ((g ^ (rl & 7)) * 16) + half * 8) = o;
    float acc = v.x*v.x + v.y*v.y + v.z*v.z + v.w*v.w;
    #pragma unroll
    for (int off = 32; off > 0; off >>= 1) acc += __shfl_down(acc, off);
    if (lane == 0) { sqn[row] = acc; s2loc += acc; }
    cs.x += v.x; cs.y += v.y; cs.z += v.z; cs.w += v.w;
  }
  atomicAdd(&lcs[lane * 4 + 0], cs.x);
  atomicAdd(&lcs[lane * 4 + 1], cs.y);
  atomicAdd(&lcs[lane * 4 + 2], cs.z);
  atomicAdd(&lcs[lane * 4 + 3], cs.w);
  if (lane == 0) s2red[wv] = s2loc;
  __syncthreads();

  #pragma unroll
  for (int i = 0; i < 4; ++i) {
    const int c  = i * 8 + (tid >> 5);
    const int rl = tid & 31;
    const uint4 q = *reinterpret_cast<const uint4*>(
        traw + rl * 512 + ((c ^ (rl & 7)) * 16));
    *reinterpret_cast<uint4*>(ebt + (size_t)(c * NROWS + rb + rl) * 8) = q;
  }
  pcs[(size_t)blockIdx.x * NDIM + tid] = lcs[tid];
  if (tid == 0)
    s2p[blockIdx.x] = s2red[0] + s2red[1] + s2red[2] + s2red[3];
}

// ---- selection helpers (MAX-key; key = dot - nj/2, larger = nearer) ----
__device__ __forceinline__ void CEmax(float& x, float& y) {
  const float h = fmaxf(x, y);
  y = fminf(x, y);
  x = h;
}
__device__ __forceinline__ void clean8max(float* s) {   // bitonic -> descending
  CEmax(s[0],s[4]); CEmax(s[1],s[5]); CEmax(s[2],s[6]); CEmax(s[3],s[7]);
  CEmax(s[0],s[2]); CEmax(s[1],s[3]); CEmax(s[4],s[6]); CEmax(s[5],s[7]);
  CEmax(s[0],s[1]); CEmax(s[2],s[3]); CEmax(s[4],s[5]); CEmax(s[6],s[7]);
}
__device__ __forceinline__ void ins8max(float* m, const float c) {  // desc insert
  m[7] = __builtin_amdgcn_fmed3f(m[6], m[7], c);
  m[6] = __builtin_amdgcn_fmed3f(m[5], m[6], c);
  m[5] = __builtin_amdgcn_fmed3f(m[4], m[5], c);
  m[4] = __builtin_amdgcn_fmed3f(m[3], m[4], c);
  m[3] = __builtin_amdgcn_fmed3f(m[2], m[3], c);
  m[2] = __builtin_amdgcn_fmed3f(m[1], m[2], c);
  m[1] = __builtin_amdgcn_fmed3f(m[0], m[1], c);
  m[0] = fmaxf(m[0], c);
}
__device__ __forceinline__ void CEmin(float& x, float& y) {
  const float lo = fminf(x, y);
  y = fmaxf(x, y);
  x = lo;
}
__device__ __forceinline__ void clean8min(float* s) {   // bitonic -> ascending
  CEmin(s[0],s[4]); CEmin(s[1],s[5]); CEmin(s[2],s[6]); CEmin(s[3],s[7]);
  CEmin(s[0],s[2]); CEmin(s[1],s[3]); CEmin(s[4],s[6]); CEmin(s[5],s[7]);
  CEmin(s[0],s[1]); CEmin(s[2],s[3]); CEmin(s[4],s[5]); CEmin(s[6],s[7]);
}

// r19 core + deferred interleaved selection: tile t's MFMA chain carries
// tile t-1's selection (w[16]) BETWEEN consecutive MFMAs. Waves issue in
// order, so interleaving in program order lets each ~36-cyc med3 insert
// fill one MFMA dependency stall — per-tile serial latency drops from
// (MFMA 600 + select 500) to ~max of the two. R=1 keeps regs ~80 (<128).
__launch_bounds__(256, 4)
__global__ void k_main(const ushort* __restrict__ ebt,
                       const float* __restrict__ sqn,
                       float* __restrict__ knn_out) {
  __shared__ ushort lbuf[2][TCOL * NDIM];   // 2 x 16 KiB
  __shared__ float  lsqn[JRANGE];           // 2 KiB, holds -nj/2
  char* const lraw = reinterpret_cast<char*>(&lbuf[0][0]);

  const int tid  = threadIdx.x;
  const int lane = tid & 63;
  const int wv   = tid >> 6;
  const int col  = lane & 31;
  const int hi   = lane >> 5;
  const int rowi = blockIdx.x * BLK_ROWS + wv * 32 + col;
  const int split = blockIdx.y;
  const int jbase = split * JRANGE;

  bf16x8 ifr[16];
  #pragma unroll
  for (int kk = 0; kk < 16; ++kk)
    ifr[kk] = *reinterpret_cast<const bf16x8*>(
        ebt + (size_t)((2 * kk + hi) * NROWS + rowi) * 8);
  const float ni = sqn[rowi];

  float mX[KNN], mY[KNN];
  #pragma unroll
  for (int i = 0; i < KNN; ++i) { mX[i] = -1e30f; mY[i] = -1e30f; }
  float w[16];
  #pragma unroll
  for (int q = 0; q < 16; ++q) w[q] = -1e30f;   // tile-0 selection is no-op

  const ushort* sp[4];
  #pragma unroll
  for (int s = 0; s < 4; ++s) {
    const int c = s * 8 + (tid >> 5);
    sp[s] = ebt + (size_t)(c * NROWS + jbase + (tid & 31)) * 8;
  }
  const int lbase = hi * 512 + col * 16;

  auto STAGE = [&](int bufc) {
    #pragma unroll
    for (int s = 0; s < 4; ++s) {
      __builtin_amdgcn_global_load_lds(
          (const __attribute__((address_space(1))) void*)sp[s],
          (__attribute__((address_space(3))) void*)(
              lraw + bufc * 16384 + s * 4096 + wv * 1024),
          16, 0, 0);
      sp[s] += TCOL * 8;
    }
  };

  const int nT = JRANGE / TCOL;            // 16

  STAGE(0);
  STAGE(1);
  // pre-negated norms -> LDS (keeps nj off vmcnt; no per-iter v_mul)
  #pragma unroll
  for (int i = 0; i < JRANGE / 256; ++i)
    lsqn[tid + i * 256] = -0.5f * sqn[jbase + tid + i * 256];
  __syncthreads();   // one-time full drain: tiles 0,1 + lsqn all visible

  for (int t = 0; t < nT; ++t) {
    if (t + 1 < nT) {
      asm volatile("s_waitcnt vmcnt(4)" ::: "memory");  // tile t landed
    } else {
      asm volatile("s_waitcnt vmcnt(0)" ::: "memory");
    }
    __builtin_amdgcn_s_barrier();
    asm volatile("" ::: "memory");

    {
      const int bufc = t & 1;
      f32x16 acc;
      #pragma unroll
      for (int g = 0; g < 4; ++g) {
        const float4 nj4 = *reinterpret_cast<const float4*>(
            &lsqn[t * TCOL + g * 8 + hi * 4]);        // ds_read of -nj/2
        acc[g*4+0] = nj4.x; acc[g*4+1] = nj4.y;
        acc[g*4+2] = nj4.z; acc[g*4+3] = nj4.w;
      }
      __builtin_amdgcn_s_setprio(1);
      // MFMA chain with tile t-1's selection interleaved per chunk:
      // ins8max(w[kk]) is independent of this tile's MFMAs, so the wave
      // issues it inside MFMA kk's dependency stall (in-order issue).
      #pragma unroll
      for (int kk = 0; kk < 16; ++kk) {
        const bf16x8 jf = *reinterpret_cast<const bf16x8*>(
            lraw + bufc * 16384 + kk * 1024 + lbase);
        acc = __builtin_amdgcn_mfma_f32_32x32x16_bf16(jf, ifr[kk], acc, 0, 0, 0);
        if (kk < 8) ins8max(mX, w[kk]);
        else        ins8max(mY, w[kk]);
      }
      __builtin_amdgcn_s_setprio(0);
      // hand this tile's keys to the next iteration's selection
      #pragma unroll
      for (int q = 0; q < 16; ++q) w[q] = acc[q];
    }

    asm volatile("" ::: "memory");
    __builtin_amdgcn_s_barrier();
    if (t + 2 < nT) STAGE(t & 1);          // only stage loads on vmcnt
  }

  // final deferred selection (last tile's keys)
  #pragma unroll
  for (int q = 0; q < 8; ++q) {
    ins8max(mX, w[q]);
    ins8max(mY, w[q + 8]);
  }

  // merge the two per-lane desc lists: top-8(X∪Y) = max(mX_k, mY_{7-k})
  float m[KNN];
  #pragma unroll
  for (int k = 0; k < KNN; ++k) m[k] = fmaxf(mX[k], mY[KNN - 1 - k]);
  clean8max(m);

  float g[KNN];
  #pragma unroll
  for (int k = 0; k < KNN; ++k)
    g[k] = fmaxf(m[k], __shfl_xor(m[KNN - 1 - k], 32));
  clean8max(g);
  if (hi == 0) {
    float* dst = knn_out + ((size_t)split * NROWS + rowi) * KNN;
    #pragma unroll
    for (int k = 0; k < KNN; ++k)
      dst[k] = fmaxf(fmaf(-2.0f, g[k], ni), 0.0f);   // ascending distances
  }
}

// 64 blocks x 128 rows; 2 threads/row (8 splits each) pair-merged via shfl.
// Q reduction distributed over blocks 0..3; S2 in block 0.
// Last finishing block (counter gacc[3]) computes the output scalar.
__global__ void k_final(const float* __restrict__ knn,
                        const float* __restrict__ pcs,
                        const float* __restrict__ s2p,
                        float* __restrict__ gacc,
                        float* __restrict__ out) {
  const int tid  = threadIdx.x;
  const int lane = tid & 63;
  const int wv   = tid >> 6;
  const int row  = blockIdx.x * 128 + (tid >> 1);
  const int sg   = (tid & 1) * 8;
  __shared__ float red[12];

  float m[KNN];
  {
    const float* p0 = knn + ((size_t)sg * NROWS + row) * KNN;
    #pragma unroll
    for (int i = 0; i < KNN; ++i) m[i] = p0[i];
  }
  #pragma unroll
  for (int s = 1; s < 8; ++s) {
    const float* p = knn + ((size_t)(sg + s) * NROWS + row) * KNN;
    float b[KNN];
    #pragma unroll
    for (int i = 0; i < KNN; ++i) b[i] = p[i];
    #pragma unroll
    for (int k = 0; k < KNN; ++k) m[k] = fminf(m[k], b[KNN - 1 - k]);
    clean8min(m);
  }
  float b[KNN];
  #pragma unroll
  for (int k = 0; k < KNN; ++k) b[k] = __shfl_xor(m[k], 1);
  #pragma unroll
  for (int k = 0; k < KNN; ++k) m[k] = fminf(m[k], b[KNN - 1 - k]);
  clean8min(m);

  float rs = 0.f;
  if ((tid & 1) == 0) {
    #pragma unroll
    for (int i = 0; i < KNN; ++i) rs += m[i];
  }
  #pragma unroll
  for (int off = 32; off > 0; off >>= 1) rs += __shfl_down(rs, off);
  if (lane == 0) red[wv] = rs;
  __syncthreads();
  if (tid == 0)
    atomicAdd(&gacc[0], red[0] + red[1] + red[2] + red[3]);

  if (blockIdx.x < 4) {
    const int dim = blockIdx.x * 64 + (tid >> 2);
    const int sl  = tid & 3;
    float s = 0.f;
    #pragma unroll 8
    for (int k = 0; k < 64; ++k)
      s += pcs[(size_t)(sl * 64 + k) * NDIM + dim];
    s += __shfl_xor(s, 1);
    s += __shfl_xor(s, 2);
    float q = (sl == 0) ? s * s : 0.f;
    #pragma unroll
    for (int off = 32; off > 0; off >>= 1) q += __shfl_down(q, off);
    if (lane == 0) red[4 + wv] = q;
    __syncthreads();
    if (tid == 0)
      atomicAdd(&gacc[2], red[4] + red[5] + red[6] + red[7]);
  }
  if (blockIdx.x == 0) {
    float s2 = s2p[tid];
    #pragma unroll
    for (int off = 32; off > 0; off >>= 1) s2 += __shfl_down(s2, off);
    if (lane == 0) red[8 + wv] = s2;
    __syncthreads();
    if (tid == 0)
      atomicAdd(&gacc[1], red[8] + red[9] + red[10] + red[11]);
  }
  // completion: last block computes the output scalar.
  if (tid == 0) {
    __threadfence();
    int* cnt = (int*)(gacc + 3);
    const int prev = atomicAdd(cnt, 1);
    if (prev == (int)gridDim.x - 1) {
      const float sum8 = atomicAdd(&gacc[0], 0.0f);
      const float S2   = atomicAdd(&gacc[1], 0.0f);
      const float Q    = atomicAdd(&gacc[2], 0.0f);
      const float ref_var = (S2 - Q / (float)NROWS) / ((float)NDIM * (float)(NROWS - 1));
      out[0] = (sum8 / (float)(NROWS * KNN)) / ref_var;
    }
  }
}

extern "C" void kernel_launch(void* const* d_in, const int* in_sizes, int n_in,
                              void* d_out, int out_size, void* d_ws, size_t ws_size,
                              hipStream_t stream) {
  const float* e = (const float*)d_in[0];
  char* ws = (char*)d_ws;
  ushort* ebt = (ushort*)(ws + WS_EBT);
  float* sqn  = (float*)(ws + WS_SQN);
  float* pcs  = (float*)(ws + WS_PCS);
  float* s2p  = (float*)(ws + WS_S2P);
  float* gacc = (float*)(ws + WS_ACC);
  float* knn  = (float*)(ws + WS_KNN);
  float* out  = (float*)d_out;

  hipLaunchKernelGGL(k_prep,  dim3(256), dim3(256), 0, stream,
                     e, ebt, sqn, pcs, s2p, gacc);
  hipLaunchKernelGGL(k_main,  dim3(NBX, JSPLIT), dim3(256), 0, stream,
                     ebt, sqn, knn);
  hipLaunchKernelGGL(k_final, dim3(64), dim3(256), 0, stream,
                     knn, pcs, s2p, gacc, out);
}

// Round 21
// 65.421 us; speedup vs baseline: 1.1303x; 1.1303x over previous
//
#include <hip/hip_runtime.h>
#include <hip/hip_bf16.h>

#define NROWS 8192
#define NDIM  256
#define KNN   8
#define TCOL  32                          // j-cols per LDS tile (16 KiB)
#define BLK_ROWS 128                      // 4 waves x 32 rows (R=1)
#define JSPLIT 16
#define JRANGE (NROWS / JSPLIT)           // 512
#define NBX    (NROWS / BLK_ROWS)         // 64 row-blocks

typedef __attribute__((ext_vector_type(8)))  short bf16x8;
typedef __attribute__((ext_vector_type(16))) float f32x16;

// ---- workspace layout (bytes) ----
// ebT chunk-major: ushort ebT[32][NROWS][8] — chunk c holds dims 8c..8c+7.
#define WS_EBT 0                          // 4 MiB
#define WS_SQN (4*1024*1024)              // 32 KiB
#define WS_PCS (WS_SQN + 32*1024)         // 256 x 256 f32 = 256 KiB
#define WS_S2P (WS_PCS + 256*1024)        // 256 f32 = 1 KiB
#define WS_ACC (WS_S2P + 1024)            // gacc[0]=sum8 [1]=S2 [2]=Q [3]=cnt
#define WS_KNN (WS_ACC + 1024)            // [16][NROWS][KNN] f32 = 4 MiB

// e -> bf16 chunk-major (LDS-staged transpose -> coalesced 512B writes),
// per-row norms, per-block colsum/S2 partials. Block 0 zeroes gacc.
__global__ void k_prep(const float* __restrict__ e,
                       ushort* __restrict__ ebt,
                       float* __restrict__ sqn,
                       float* __restrict__ pcs,
                       float* __restrict__ s2p,
                       float* __restrict__ gacc) {
  __shared__ ushort tbuf[32 * 256];       // 16 KiB transpose tile
  __shared__ float  lcs[NDIM];
  __shared__ float  s2red[4];
  char* const traw = reinterpret_cast<char*>(&tbuf[0]);

  const int tid  = threadIdx.x;
  const int lane = tid & 63;
  const int wv   = tid >> 6;
  const int rb   = blockIdx.x * 32;
  if (blockIdx.x == 0 && tid < 4) ((int*)gacc)[tid] = 0;
  lcs[tid] = 0.f;
  __syncthreads();

  const int g    = lane >> 1;             // 16B granule 0..31
  const int half = lane & 1;
  float4 cs = {0.f, 0.f, 0.f, 0.f};
  float s2loc = 0.f;
  #pragma unroll
  for (int r = 0; r < 8; ++r) {
    const int rl  = wv * 8 + r;
    const int row = rb + rl;
    const float4 v = *reinterpret_cast<const float4*>(e + (size_t)row * NDIM + lane * 4);
    ushort4 o;
    __hip_bfloat16 b0 = __float2bfloat16(v.x), b1 = __float2bfloat16(v.y);
    __hip_bfloat16 b2 = __float2bfloat16(v.z), b3 = __float2bfloat16(v.w);
    o.x = *reinterpret_cast<ushort*>(&b0); o.y = *reinterpret_cast<ushort*>(&b1);
    o.z = *reinterpret_cast<ushort*>(&b2); o.w = *reinterpret_cast<ushort*>(&b3);
    *reinterpret_cast<ushort4*>(
        traw + rl * 512 + ((g ^ (rl & 7)) * 16) + half * 8) = o;
    float acc = v.x*v.x + v.y*v.y + v.z*v.z + v.w*v.w;
    #pragma unroll
    for (int off = 32; off > 0; off >>= 1) acc += __shfl_down(acc, off);
    if (lane == 0) { sqn[row] = acc; s2loc += acc; }
    cs.x += v.x; cs.y += v.y; cs.z += v.z; cs.w += v.w;
  }
  atomicAdd(&lcs[lane * 4 + 0], cs.x);
  atomicAdd(&lcs[lane * 4 + 1], cs.y);
  atomicAdd(&lcs[lane * 4 + 2], cs.z);
  atomicAdd(&lcs[lane * 4 + 3], cs.w);
  if (lane == 0) s2red[wv] = s2loc;
  __syncthreads();

  #pragma unroll
  for (int i = 0; i < 4; ++i) {
    const int c  = i * 8 + (tid >> 5);
    const int rl = tid & 31;
    const uint4 q = *reinterpret_cast<const uint4*>(
        traw + rl * 512 + ((c ^ (rl & 7)) * 16));
    *reinterpret_cast<uint4*>(ebt + (size_t)(c * NROWS + rb + rl) * 8) = q;
  }
  pcs[(size_t)blockIdx.x * NDIM + tid] = lcs[tid];
  if (tid == 0)
    s2p[blockIdx.x] = s2red[0] + s2red[1] + s2red[2] + s2red[3];
}

// ---- selection helpers (MAX-key; key = dot - nj/2, larger = nearer) ----
__device__ __forceinline__ void CEmax(float& x, float& y) {
  const float h = fmaxf(x, y);
  y = fminf(x, y);
  x = h;
}
__device__ __forceinline__ void clean8max(float* s) {   // bitonic -> descending
  CEmax(s[0],s[4]); CEmax(s[1],s[5]); CEmax(s[2],s[6]); CEmax(s[3],s[7]);
  CEmax(s[0],s[2]); CEmax(s[1],s[3]); CEmax(s[4],s[6]); CEmax(s[5],s[7]);
  CEmax(s[0],s[1]); CEmax(s[2],s[3]); CEmax(s[4],s[5]); CEmax(s[6],s[7]);
}
__device__ __forceinline__ void ins8max(float* m, const float c) {  // desc insert
  m[7] = __builtin_amdgcn_fmed3f(m[6], m[7], c);
  m[6] = __builtin_amdgcn_fmed3f(m[5], m[6], c);
  m[5] = __builtin_amdgcn_fmed3f(m[4], m[5], c);
  m[4] = __builtin_amdgcn_fmed3f(m[3], m[4], c);
  m[3] = __builtin_amdgcn_fmed3f(m[2], m[3], c);
  m[2] = __builtin_amdgcn_fmed3f(m[1], m[2], c);
  m[1] = __builtin_amdgcn_fmed3f(m[0], m[1], c);
  m[0] = fmaxf(m[0], c);
}
__device__ __forceinline__ void CEmin(float& x, float& y) {
  const float lo = fminf(x, y);
  y = fmaxf(x, y);
  x = lo;
}
__device__ __forceinline__ void clean8min(float* s) {   // bitonic -> ascending
  CEmin(s[0],s[4]); CEmin(s[1],s[5]); CEmin(s[2],s[6]); CEmin(s[3],s[7]);
  CEmin(s[0],s[2]); CEmin(s[1],s[3]); CEmin(s[4],s[6]); CEmin(s[5],s[7]);
  CEmin(s[0],s[1]); CEmin(s[2],s[3]); CEmin(s[4],s[5]); CEmin(s[6],s[7]);
}

// r19 core (best verified): R=1, 4 blocks/CU, chunk-major ebT, counted-vmcnt
// pipeline with nj off vmcnt (lsqn holds -nj/2), split selection chains
// mX/mY. r20's deferred-interleave spilled (live set >128 regs) — reverted.
__launch_bounds__(256, 4)
__global__ void k_main(const ushort* __restrict__ ebt,
                       const float* __restrict__ sqn,
                       float* __restrict__ knn_out) {
  __shared__ ushort lbuf[2][TCOL * NDIM];   // 2 x 16 KiB
  __shared__ float  lsqn[JRANGE];           // 2 KiB, holds -nj/2
  char* const lraw = reinterpret_cast<char*>(&lbuf[0][0]);

  const int tid  = threadIdx.x;
  const int lane = tid & 63;
  const int wv   = tid >> 6;
  const int col  = lane & 31;
  const int hi   = lane >> 5;
  const int rowi = blockIdx.x * BLK_ROWS + wv * 32 + col;
  const int split = blockIdx.y;
  const int jbase = split * JRANGE;

  bf16x8 ifr[16];
  #pragma unroll
  for (int kk = 0; kk < 16; ++kk)
    ifr[kk] = *reinterpret_cast<const bf16x8*>(
        ebt + (size_t)((2 * kk + hi) * NROWS + rowi) * 8);
  const float ni = sqn[rowi];

  float mX[KNN], mY[KNN];
  #pragma unroll
  for (int i = 0; i < KNN; ++i) { mX[i] = -1e30f; mY[i] = -1e30f; }

  const ushort* sp[4];
  #pragma unroll
  for (int s = 0; s < 4; ++s) {
    const int c = s * 8 + (tid >> 5);
    sp[s] = ebt + (size_t)(c * NROWS + jbase + (tid & 31)) * 8;
  }
  const int lbase = hi * 512 + col * 16;

  auto STAGE = [&](int bufc) {
    #pragma unroll
    for (int s = 0; s < 4; ++s) {
      __builtin_amdgcn_global_load_lds(
          (const __attribute__((address_space(1))) void*)sp[s],
          (__attribute__((address_space(3))) void*)(
              lraw + bufc * 16384 + s * 4096 + wv * 1024),
          16, 0, 0);
      sp[s] += TCOL * 8;
    }
  };

  const int nT = JRANGE / TCOL;            // 16

  STAGE(0);
  STAGE(1);
  // pre-negated norms -> LDS (keeps nj off vmcnt; deletes per-iter v_mul)
  #pragma unroll
  for (int i = 0; i < JRANGE / 256; ++i)
    lsqn[tid + i * 256] = -0.5f * sqn[jbase + tid + i * 256];
  __syncthreads();   // one-time full drain: tiles 0,1 + lsqn all visible

  for (int t = 0; t < nT; ++t) {
    if (t + 1 < nT) {
      asm volatile("s_waitcnt vmcnt(4)" ::: "memory");  // tile t landed
    } else {
      asm volatile("s_waitcnt vmcnt(0)" ::: "memory");
    }
    __builtin_amdgcn_s_barrier();
    asm volatile("" ::: "memory");

    {
      const int bufc = t & 1;
      f32x16 acc;
      #pragma unroll
      for (int g = 0; g < 4; ++g) {
        const float4 nj4 = *reinterpret_cast<const float4*>(
            &lsqn[t * TCOL + g * 8 + hi * 4]);        // ds_read of -nj/2
        acc[g*4+0] = nj4.x; acc[g*4+1] = nj4.y;
        acc[g*4+2] = nj4.z; acc[g*4+3] = nj4.w;
      }
      __builtin_amdgcn_s_setprio(1);
      #pragma unroll
      for (int kk = 0; kk < 16; ++kk) {
        const bf16x8 jf = *reinterpret_cast<const bf16x8*>(
            lraw + bufc * 16384 + kk * 1024 + lbase);
        acc = __builtin_amdgcn_mfma_f32_32x32x16_bf16(jf, ifr[kk], acc, 0, 0, 0);
      }
      __builtin_amdgcn_s_setprio(0);
      // two independent selection chains (halved serial med3 depth)
      #pragma unroll
      for (int q = 0; q < 8; ++q) {
        ins8max(mX, acc[q]);
        ins8max(mY, acc[q + 8]);
      }
    }

    asm volatile("" ::: "memory");
    __builtin_amdgcn_s_barrier();
    if (t + 2 < nT) STAGE(t & 1);          // only stage loads on vmcnt
  }

  // merge the two per-lane desc lists: top-8(X∪Y) = max(mX_k, mY_{7-k})
  float m[KNN];
  #pragma unroll
  for (int k = 0; k < KNN; ++k) m[k] = fmaxf(mX[k], mY[KNN - 1 - k]);
  clean8max(m);

  float g[KNN];
  #pragma unroll
  for (int k = 0; k < KNN; ++k)
    g[k] = fmaxf(m[k], __shfl_xor(m[KNN - 1 - k], 32));
  clean8max(g);
  if (hi == 0) {
    float* dst = knn_out + ((size_t)split * NROWS + rowi) * KNN;
    #pragma unroll
    for (int k = 0; k < KNN; ++k)
      dst[k] = fmaxf(fmaf(-2.0f, g[k], ni), 0.0f);   // ascending distances
  }
}

// 64 blocks x 128 rows; 2 threads/row (8 splits each) pair-merged via shfl.
// Q reduction distributed over blocks 0..3; S2 in block 0.
// Last finishing block (counter gacc[3]) computes the output scalar.
__global__ void k_final(const float* __restrict__ knn,
                        const float* __restrict__ pcs,
                        const float* __restrict__ s2p,
                        float* __restrict__ gacc,
                        float* __restrict__ out) {
  const int tid  = threadIdx.x;
  const int lane = tid & 63;
  const int wv   = tid >> 6;
  const int row  = blockIdx.x * 128 + (tid >> 1);
  const int sg   = (tid & 1) * 8;
  __shared__ float red[12];

  float m[KNN];
  {
    const float* p0 = knn + ((size_t)sg * NROWS + row) * KNN;
    #pragma unroll
    for (int i = 0; i < KNN; ++i) m[i] = p0[i];
  }
  #pragma unroll
  for (int s = 1; s < 8; ++s) {
    const float* p = knn + ((size_t)(sg + s) * NROWS + row) * KNN;
    float b[KNN];
    #pragma unroll
    for (int i = 0; i < KNN; ++i) b[i] = p[i];
    #pragma unroll
    for (int k = 0; k < KNN; ++k) m[k] = fminf(m[k], b[KNN - 1 - k]);
    clean8min(m);
  }
  float b[KNN];
  #pragma unroll
  for (int k = 0; k < KNN; ++k) b[k] = __shfl_xor(m[k], 1);
  #pragma unroll
  for (int k = 0; k < KNN; ++k) m[k] = fminf(m[k], b[KNN - 1 - k]);
  clean8min(m);

  float rs = 0.f;
  if ((tid & 1) == 0) {
    #pragma unroll
    for (int i = 0; i < KNN; ++i) rs += m[i];
  }
  #pragma unroll
  for (int off = 32; off > 0; off >>= 1) rs += __shfl_down(rs, off);
  if (lane == 0) red[wv] = rs;
  __syncthreads();
  if (tid == 0)
    atomicAdd(&gacc[0], red[0] + red[1] + red[2] + red[3]);

  if (blockIdx.x < 4) {
    const int dim = blockIdx.x * 64 + (tid >> 2);
    const int sl  = tid & 3;
    float s = 0.f;
    #pragma unroll 8
    for (int k = 0; k < 64; ++k)
      s += pcs[(size_t)(sl * 64 + k) * NDIM + dim];
    s += __shfl_xor(s, 1);
    s += __shfl_xor(s, 2);
    float q = (sl == 0) ? s * s : 0.f;
    #pragma unroll
    for (int off = 32; off > 0; off >>= 1) q += __shfl_down(q, off);
    if (lane == 0) red[4 + wv] = q;
    __syncthreads();
    if (tid == 0)
      atomicAdd(&gacc[2], red[4] + red[5] + red[6] + red[7]);
  }
  if (blockIdx.x == 0) {
    float s2 = s2p[tid];
    #pragma unroll
    for (int off = 32; off > 0; off >>= 1) s2 += __shfl_down(s2, off);
    if (lane == 0) red[8 + wv] = s2;
    __syncthreads();
    if (tid == 0)
      atomicAdd(&gacc[1], red[8] + red[9] + red[10] + red[11]);
  }
  // completion: last block computes the output scalar.
  if (tid == 0) {
    __threadfence();
    int* cnt = (int*)(gacc + 3);
    const int prev = atomicAdd(cnt, 1);
    if (prev == (int)gridDim.x - 1) {
      const float sum8 = atomicAdd(&gacc[0], 0.0f);
      const float S2   = atomicAdd(&gacc[1], 0.0f);
      const float Q    = atomicAdd(&gacc[2], 0.0f);
      const float ref_var = (S2 - Q / (float)NROWS) / ((float)NDIM * (float)(NROWS - 1));
      out[0] = (sum8 / (float)(NROWS * KNN)) / ref_var;
    }
  }
}

extern "C" void kernel_launch(void* const* d_in, const int* in_sizes, int n_in,
                              void* d_out, int out_size, void* d_ws, size_t ws_size,
                              hipStream_t stream) {
  const float* e = (const float*)d_in[0];
  char* ws = (char*)d_ws;
  ushort* ebt = (ushort*)(ws + WS_EBT);
  float* sqn  = (float*)(ws + WS_SQN);
  float* pcs  = (float*)(ws + WS_PCS);
  float* s2p  = (float*)(ws + WS_S2P);
  float* gacc = (float*)(ws + WS_ACC);
  float* knn  = (float*)(ws + WS_KNN);
  float* out  = (float*)d_out;

  hipLaunchKernelGGL(k_prep,  dim3(256), dim3(256), 0, stream,
                     e, ebt, sqn, pcs, s2p, gacc);
  hipLaunchKernelGGL(k_main,  dim3(NBX, JSPLIT), dim3(256), 0, stream,
                     ebt, sqn, knn);
  hipLaunchKernelGGL(k_final, dim3(64), dim3(256), 0, stream,
                     knn, pcs, s2p, gacc, out);
}